// Round 16
// baseline (542.145 us; speedup 1.0000x reference)
//
#include <hip/hip_runtime.h>

#define DF 128
constexpr int N_NODES = 10000;
constexpr int N_EDGES = 640000;

typedef __bf16 bf16x8 __attribute__((ext_vector_type(8)));
typedef float f32x4 __attribute__((ext_vector_type(4)));

// ---------- helpers ----------
__device__ __forceinline__ unsigned short f2bf(float f) {
  unsigned u = __builtin_bit_cast(unsigned, f);
  u += 0x7fffu + ((u >> 16) & 1u);   // RTNE
  return (unsigned short)(u >> 16);
}

__device__ __forceinline__ bf16x8 cvt8(float4 a, float4 b) {
  bf16x8 r;
  r[0] = (__bf16)a.x; r[1] = (__bf16)a.y; r[2] = (__bf16)a.z; r[3] = (__bf16)a.w;
  r[4] = (__bf16)b.x; r[5] = (__bf16)b.y; r[6] = (__bf16)b.z; r[7] = (__bf16)b.w;
  return r;
}

// stage a 16x128 C-layout tile into a 4KB LDS buffer, XOR-swizzled (HW-verified addresses)
template <bool RELU>
__device__ __forceinline__ void stage_t(char* bufj, const f32x4* accv, int grp, int row16) {
#pragma unroll
  for (int nt = 0; nt < 8; ++nt)
#pragma unroll
    for (int i = 0; i < 4; ++i) {
      const int r = grp * 4 + i;
      const int c = nt * 16 + row16;
      float v = RELU ? fmaxf(accv[nt][i], 0.f) : accv[nt][i];
      *(unsigned short*)(bufj + ((r * 256 + c * 2) ^ ((r & 7) << 4))) = f2bf(v);
    }
}

// read an A-fragment (16 rows x 32 k) from a swizzled 4KB buffer (HW-verified)
__device__ __forceinline__ bf16x8 read_a(const char* bufj, int kt, int grp, int row16) {
  return *(const bf16x8*)(bufj + ((row16 * 256 + kt * 64 + grp * 16) ^ ((row16 & 7) << 4)));
}

// ---------- kernel 0: zero deg ----------
__global__ void zero_deg(int* __restrict__ deg) {
  int i = blockIdx.x * 256 + threadIdx.x;
  if (i < N_NODES) deg[i] = 0;
}

// ---------- kernel 1: pack weights + nodes->bf16 + receiver histogram (fused) ----------
__global__ void pack_prep(const float* __restrict__ w0, const float* __restrict__ w1,
                          const float* __restrict__ w2, const float* __restrict__ nw0,
                          const float* __restrict__ nw1, const float* __restrict__ nw2,
                          const float* __restrict__ wn, const float* __restrict__ nodes,
                          const int* __restrict__ receivers,
                          unsigned short* __restrict__ dst, unsigned short* __restrict__ nbf,
                          int* __restrict__ deg) {
  int tid = blockIdx.x * blockDim.x + threadIdx.x;
  if (tid < 163840) {
    const float* src; int p;
    if (tid < 49152)       { src = w0;  p = tid; }
    else if (tid < 65536)  { src = w1;  p = tid - 49152; }
    else if (tid < 81920)  { src = w2;  p = tid - 65536; }
    else if (tid < 114688) { src = nw0; p = tid - 81920; }
    else if (tid < 131072) { src = nw1; p = tid - 114688; }
    else if (tid < 147456) { src = nw2; p = tid - 131072; }
    else                   { src = wn;  p = tid - 147456; }
    int i = p & 7, lane = (p >> 3) & 63, tile = p >> 9;
    int nt = tile & 7, kt = tile >> 3;
    int k = kt * 32 + ((lane >> 4) << 3) + i;
    int n = nt * 16 + (lane & 15);
    dst[tid] = f2bf(src[k * 128 + n]);
    return;
  }
  int p = tid - 163840;
  if (p < N_NODES * DF) {                    // nodes -> bf16
    nbf[p] = f2bf(nodes[p]);
    return;
  }
  p -= N_NODES * DF;
  if (p < N_EDGES) atomicAdd(&deg[receivers[p]], 1);
}

// ---------- CSR build: exclusive scan of deg -> cursor ----------
__global__ void scan_kernel(const int* __restrict__ deg, int* __restrict__ cursor) {
  __shared__ int part[1024];
  const int t = threadIdx.x;
  int loc[16];
  int s = 0;
#pragma unroll
  for (int j = 0; j < 16; ++j) {
    int idx = t * 16 + j;
    int v = (idx < N_NODES) ? deg[idx] : 0;
    loc[j] = s;
    s += v;
  }
  part[t] = s;
  __syncthreads();
  for (int off = 1; off < 1024; off <<= 1) {
    int v = part[t];
    int a = (t >= off) ? part[t - off] : 0;
    __syncthreads();
    part[t] = v + a;
    __syncthreads();
  }
  int base = (t > 0) ? part[t - 1] : 0;
#pragma unroll
  for (int j = 0; j < 16; ++j) {
    int idx = t * 16 + j;
    if (idx < N_NODES) cursor[idx] = base + loc[j];
  }
}

// ---------- kernel 3: scatter + FUSED LAYER-0 + sorted write (blocks 0..2499)
//            + pq & hsum-zero (blocks 2500..2656) ----------
// Blocks 0..2499: 256 edges. Phase 1: cursor atomic -> sorted pos q, write
// ssend/rid. Phase 2: read edge rows COALESCED, compute raw0 = E@W0c + b0 via
// MFMA, transpose through swizzled LDS (verified path), write 16x128 bf16 tiles
// row-major at sorted positions -> msg reads A-frags directly, no L0/transposes.
__global__ void __launch_bounds__(256) scatter_l0(
    const int* __restrict__ receivers, const int* __restrict__ senders,
    const float* __restrict__ edges, const float* __restrict__ b0,
    int* __restrict__ cursor, int* __restrict__ ssend, int* __restrict__ rid,
    unsigned short* __restrict__ rsort,
    const unsigned short* __restrict__ nbf, const unsigned short* __restrict__ pw,
    unsigned short* __restrict__ P, unsigned short* __restrict__ Q,
    float* __restrict__ hsum) {
  __shared__ int qsh[256];
  __shared__ char tbuf[32768];   // 4 waves x 2 x 4KB transpose buffers
  const int bid = blockIdx.x;
  const int tid = threadIdx.x;
  if (bid < N_EDGES / 256) {
    const int e = bid * 256 + tid;
    const int r = receivers[e];
    const int q = atomicAdd(&cursor[r], 1);
    ssend[q] = senders[e];
    rid[q] = r;
    qsh[tid] = q;
    __syncthreads();
    const int lane = tid & 63, wave = tid >> 6;
    const int row16 = lane & 15, grp = lane >> 4;
    char* tb = tbuf + wave * 8192;
    const unsigned short* w0c = pw + 32768;
#pragma unroll
    for (int pass = 0; pass < 2; ++pass) {
      // ---- load 2 subtiles of edges (coalesced f32) + cvt ----
      bf16x8 ebf[2][4];
#pragma unroll
      for (int s = 0; s < 2; ++s) {
        const int eloc = bid * 256 + wave * 64 + (pass * 2 + s) * 16 + row16;
#pragma unroll
        for (int kt = 0; kt < 4; ++kt) {
          const float* p = edges + (size_t)eloc * DF + kt * 32 + grp * 8;
          ebf[s][kt] = cvt8(*(const float4*)p, *(const float4*)(p + 4));
        }
      }
      // ---- raw0 = E @ W0c + b0 ----
      f32x4 acc[2][8];
#pragma unroll
      for (int nt = 0; nt < 8; ++nt) {
        float bv = b0[nt * 16 + row16];
        acc[0][nt] = (f32x4){bv, bv, bv, bv};
        acc[1][nt] = (f32x4){bv, bv, bv, bv};
      }
#pragma unroll
      for (int kt = 0; kt < 4; ++kt) {
#pragma unroll
        for (int nt = 0; nt < 8; ++nt) {
          bf16x8 bw = *(const bf16x8*)(w0c + ((size_t)(kt * 8 + nt) * 64 + lane) * 8);
          acc[0][nt] = __builtin_amdgcn_mfma_f32_16x16x32_bf16(ebf[0][kt], bw, acc[0][nt], 0, 0, 0);
          acc[1][nt] = __builtin_amdgcn_mfma_f32_16x16x32_bf16(ebf[1][kt], bw, acc[1][nt], 0, 0, 0);
        }
      }
      // ---- transpose via LDS, then write rows to sorted positions ----
      stage_t<false>(tb, acc[0], grp, row16);
      stage_t<false>(tb + 4096, acc[1], grp, row16);
      asm volatile("s_waitcnt lgkmcnt(0)" ::: "memory");
      __builtin_amdgcn_sched_barrier(0);
#pragma unroll
      for (int s = 0; s < 2; ++s) {
#pragma unroll
        for (int j = 0; j < 4; ++j) {
          const int idx = j * 64 + lane;
          const int row = idx >> 4;        // 0..15
          const int chunk = idx & 15;      // 16B chunk
          const int qq = qsh[wave * 64 + (pass * 2 + s) * 16 + row];
          bf16x8 v = *(const bf16x8*)(tb + s * 4096 +
                                      ((row * 256 + chunk * 16) ^ ((row & 7) << 4)));
          *(bf16x8*)(rsort + (size_t)qq * DF + chunk * 8) = v;
        }
      }
      asm volatile("s_waitcnt lgkmcnt(0)" ::: "memory");   // LDS reads done before next pass
      __builtin_amdgcn_sched_barrier(0);
    }
    return;
  }
  const int pb = bid - N_EDGES / 256;   // 0..156
  const int base_row = pb * 64;
  const int nrows = min(64, N_NODES - base_row);
  {
    float4* hz = (float4*)(hsum + (size_t)base_row * DF);
    for (int c = tid; c < nrows * 32; c += 256) hz[c] = make_float4(0.f, 0.f, 0.f, 0.f);
  }
  const int lane = tid & 63, wave = tid >> 6;
  const int row16 = lane & 15, grp = lane >> 4;
  const int rb = base_row + wave * 16;
  const int rA = min(rb + row16, N_NODES - 1);

  f32x4 aP[8], aQ[8];
#pragma unroll
  for (int nt = 0; nt < 8; ++nt) {
    aP[nt] = (f32x4){0.f, 0.f, 0.f, 0.f};
    aQ[nt] = (f32x4){0.f, 0.f, 0.f, 0.f};
  }
#pragma unroll
  for (int kt = 0; kt < 4; ++kt) {
    bf16x8 af = *(const bf16x8*)(nbf + (size_t)rA * DF + kt * 32 + grp * 8);
#pragma unroll
    for (int nt = 0; nt < 8; ++nt) {
      bf16x8 bwP = *(const bf16x8*)(pw + ((size_t)(kt * 8 + nt) * 64 + lane) * 8);
      bf16x8 bwQ = *(const bf16x8*)(pw + ((size_t)((4 + kt) * 8 + nt) * 64 + lane) * 8);
      aP[nt] = __builtin_amdgcn_mfma_f32_16x16x32_bf16(af, bwP, aP[nt], 0, 0, 0);
      aQ[nt] = __builtin_amdgcn_mfma_f32_16x16x32_bf16(af, bwQ, aQ[nt], 0, 0, 0);
    }
  }
#pragma unroll
  for (int nt = 0; nt < 8; ++nt)
#pragma unroll
    for (int i = 0; i < 4; ++i) {
      const int r = rb + grp * 4 + i;
      if (r < N_NODES) {
        P[(size_t)r * DF + nt * 16 + row16] = f2bf(aP[nt][i]);
        Q[(size_t)r * DF + nt * 16 + row16] = f2bf(aQ[nt][i]);
      }
    }
}

// ---------- kernel 4: persistent L1 + scatter-add (no L0, no LDS transpose) ----------
// grid 256 x 512 thr; 8 waves x 32 positions/tile, block loops tiles stride 256.
// raw0 A-frags read SEQUENTIALLY from rsort (prefetched one tile ahead);
// h1 = relu(raw + P[s] + Q[r]) fused in registers; W1 in 32KB LDS.
__global__ void __launch_bounds__(512, 2) msg_kernel(
    const unsigned short* __restrict__ rsort,
    const int* __restrict__ ssend, const int* __restrict__ rid,
    const float* __restrict__ b1,
    const unsigned short* __restrict__ pw,
    const unsigned short* __restrict__ P, const unsigned short* __restrict__ Q,
    float* __restrict__ hsum) {
  __shared__ char lds[32768];   // W1 frags only
  const int tid = threadIdx.x;
  const int lane = tid & 63, wave = tid >> 6;
  const int row16 = lane & 15, grp = lane >> 4;

  // ---- stage W1 (32KB) once per block ----
  {
    const float4* src = (const float4*)(pw + 49152);
    float4* dst = (float4*)lds;
    for (int c = tid; c < 2048; c += 512) dst[c] = src[c];
  }

  constexpr int NTILE = N_EDGES / 256;   // 2500
  int tile = blockIdx.x;

  // loop-carried state
  bf16x8 raw_c[2][4], raw_n[2][4];
  int sxc[2], rxc[2], sx2[2], rx2[2];

  // ---- prologue: first tile's indices + raw0 A-frags ----
  {
    const int pb = tile * 256 + wave * 32;
#pragma unroll
    for (int s = 0; s < 2; ++s) {
      const int pos = pb + s * 16 + row16;
      sxc[s] = ssend[pos];
      rxc[s] = rid[pos];
#pragma unroll
      for (int kt = 0; kt < 4; ++kt)
        raw_c[s][kt] = *(const bf16x8*)(rsort + (size_t)pos * DF + kt * 32 + grp * 8);
    }
  }

  __syncthreads();   // W1 staged

  for (; tile < NTILE; tile += 256) {
    const int pbase = tile * 256 + wave * 32;
    const bool hasNext = (tile + 256) < NTILE;

    // A. prefetch next tile (sequential streams)
    if (hasNext) {
      const int npb = (tile + 256) * 256 + wave * 32;
#pragma unroll
      for (int s = 0; s < 2; ++s) {
        const int pos = npb + s * 16 + row16;
        sx2[s] = ssend[pos];
        rx2[s] = rid[pos];
#pragma unroll
        for (int kt = 0; kt < 4; ++kt)
          raw_n[s][kt] = *(const bf16x8*)(rsort + (size_t)pos * DF + kt * 32 + grp * 8);
      }
    }

    // C. P/Q gathers for current tile
    bf16x8 pqf[2][2][4];   // [s][0=P,1=Q][kt]
#pragma unroll
    for (int s = 0; s < 2; ++s)
#pragma unroll
      for (int kt = 0; kt < 4; ++kt) {
        pqf[s][0][kt] = *(const bf16x8*)(P + (size_t)sxc[s] * DF + kt * 32 + grp * 8);
        pqf[s][1][kt] = *(const bf16x8*)(Q + (size_t)rxc[s] * DF + kt * 32 + grp * 8);
      }

    // G. layer 1 with fused h1 = relu(raw + P[s] + Q[r])
    f32x4 acc[2][8];
#pragma unroll
    for (int nt = 0; nt < 8; ++nt) {
      float bv = b1[nt * 16 + row16];
      acc[0][nt] = (f32x4){bv, bv, bv, bv};
      acc[1][nt] = (f32x4){bv, bv, bv, bv};
    }
#pragma unroll
    for (int kt = 0; kt < 4; ++kt) {
      bf16x8 af[2];
#pragma unroll
      for (int s = 0; s < 2; ++s) {
        bf16x8 raw = raw_c[s][kt];
        bf16x8 pv = pqf[s][0][kt], qv = pqf[s][1][kt];
        bf16x8 h;
#pragma unroll
        for (int j = 0; j < 8; ++j)
          h[j] = (__bf16)fmaxf((float)raw[j] + (float)pv[j] + (float)qv[j], 0.f);
        af[s] = h;
      }
#pragma unroll
      for (int nt = 0; nt < 8; ++nt) {
        bf16x8 bw = *(const bf16x8*)(lds + ((kt * 8 + nt) * 64 + lane) * 16);
        acc[0][nt] = __builtin_amdgcn_mfma_f32_16x16x32_bf16(af[0], bw, acc[0][nt], 0, 0, 0);
        acc[1][nt] = __builtin_amdgcn_mfma_f32_16x16x32_bf16(af[1], bw, acc[1][nt], 0, 0, 0);
      }
    }

    // H. epilogue: scatter-add h2 = relu(acc) via register segmented reduction
#pragma unroll
    for (int s = 0; s < 2; ++s) {
      const int q = pbase + s * 16 + grp * 4;
      const int ru = rid[pbase + s * 16];                 // wave-uniform
      const bool uni = (ru == rid[pbase + s * 16 + 15]);  // whole subtile one receiver
      if (uni) {
#pragma unroll
        for (int nt = 0; nt < 8; ++nt) {
          float t = fmaxf(acc[s][nt][0], 0.f) + fmaxf(acc[s][nt][1], 0.f) +
                    fmaxf(acc[s][nt][2], 0.f) + fmaxf(acc[s][nt][3], 0.f);
          t += __shfl_xor(t, 16);
          t += __shfl_xor(t, 32);
          if (grp == 0)
            unsafeAtomicAdd(hsum + (size_t)ru * DF + nt * 16 + row16, t);
        }
      } else {
        const int ra = rid[q], rb_ = rid[q + 1], rc = rid[q + 2], rd = rid[q + 3];
#pragma unroll
        for (int nt = 0; nt < 8; ++nt) {
          const int col = nt * 16 + row16;
          float run = fmaxf(acc[s][nt][0], 0.f);
          if (rb_ != ra) { unsafeAtomicAdd(hsum + (size_t)ra * DF + col, run); run = 0.f; }
          run += fmaxf(acc[s][nt][1], 0.f);
          if (rc != rb_) { unsafeAtomicAdd(hsum + (size_t)rb_ * DF + col, run); run = 0.f; }
          run += fmaxf(acc[s][nt][2], 0.f);
          if (rd != rc) { unsafeAtomicAdd(hsum + (size_t)rc * DF + col, run); run = 0.f; }
          run += fmaxf(acc[s][nt][3], 0.f);
          unsafeAtomicAdd(hsum + (size_t)rd * DF + col, run);
        }
      }
    }

    // I. rotate state
#pragma unroll
    for (int s = 0; s < 2; ++s) {
      sxc[s] = sx2[s]; rxc[s] = rx2[s];
#pragma unroll
      for (int kt = 0; kt < 4; ++kt) raw_c[s][kt] = raw_n[s][kt];
    }
  }
}

// ---------- kernel 5: agg = hsum@W2 + deg*b2 (hi/lo bf16), node MLP, residual, LN ----------
// 128 thr = 2 waves x 16 rows, grid 313
__global__ void __launch_bounds__(128) node_kernel(
    const float* __restrict__ nodes, const float* __restrict__ hsum,
    const int* __restrict__ deg, const float* __restrict__ b2,
    const float* __restrict__ nb0, const float* __restrict__ nb1, const float* __restrict__ nb2,
    const unsigned short* __restrict__ pw2,
    const unsigned short* __restrict__ pnw0, const unsigned short* __restrict__ pnw1,
    const unsigned short* __restrict__ pnw2, const unsigned short* __restrict__ pwn,
    const float* __restrict__ ln_s, const float* __restrict__ ln_b,
    float* __restrict__ out) {
  __shared__ char hs[8192];
  const int tid = threadIdx.x, lane = tid & 63, wave = tid >> 6;
  const int row16 = lane & 15, grp = lane >> 4;
  char* hb = hs + wave * 4096;
  const int rb = blockIdx.x * 32 + wave * 16;
  const int rA = min(rb + row16, N_NODES - 1);

  // ---- phase A: aggregated = hsum @ W2 + deg*b2 (hi/lo split for precision) ----
  f32x4 accA[8];
  {
    float d0 = (float)deg[min(rb + grp * 4 + 0, N_NODES - 1)];
    float d1 = (float)deg[min(rb + grp * 4 + 1, N_NODES - 1)];
    float d2 = (float)deg[min(rb + grp * 4 + 2, N_NODES - 1)];
    float d3 = (float)deg[min(rb + grp * 4 + 3, N_NODES - 1)];
#pragma unroll
    for (int nt = 0; nt < 8; ++nt) {
      float bc = b2[nt * 16 + row16];
      accA[nt] = (f32x4){d0 * bc, d1 * bc, d2 * bc, d3 * bc};
    }
  }
#pragma unroll
  for (int kt = 0; kt < 4; ++kt) {
    const float* hp = hsum + (size_t)rA * DF + kt * 32 + grp * 8;
    float4 h0 = *(const float4*)hp, h1v = *(const float4*)(hp + 4);
    bf16x8 hi = cvt8(h0, h1v);
    float4 l0, l1;
    l0.x = h0.x - (float)hi[0]; l0.y = h0.y - (float)hi[1];
    l0.z = h0.z - (float)hi[2]; l0.w = h0.w - (float)hi[3];
    l1.x = h1v.x - (float)hi[4]; l1.y = h1v.y - (float)hi[5];
    l1.z = h1v.z - (float)hi[6]; l1.w = h1v.w - (float)hi[7];
    bf16x8 lo = cvt8(l0, l1);
#pragma unroll
    for (int nt = 0; nt < 8; ++nt) {
      bf16x8 bw = *(const bf16x8*)(pw2 + ((size_t)(kt * 8 + nt) * 64 + lane) * 8);
      accA[nt] = __builtin_amdgcn_mfma_f32_16x16x32_bf16(hi, bw, accA[nt], 0, 0, 0);
      accA[nt] = __builtin_amdgcn_mfma_f32_16x16x32_bf16(lo, bw, accA[nt], 0, 0, 0);
    }
  }
  stage_t<false>(hb, accA, grp, row16);   // raw (aggregated can be negative)
  asm volatile("s_waitcnt lgkmcnt(0)" ::: "memory");
  __builtin_amdgcn_sched_barrier(0);

  // ---- node layer 0: K=256 = [nodes | aggregated] ----
  f32x4 acc[8];
#pragma unroll
  for (int nt = 0; nt < 8; ++nt) {
    float b = nb0[nt * 16 + row16];
    acc[nt] = (f32x4){b, b, b, b};
  }
#pragma unroll
  for (int kt = 0; kt < 8; ++kt) {
    bf16x8 af;
    if (kt < 4) {
      const float* p = nodes + (size_t)rA * DF + kt * 32 + grp * 8;
      af = cvt8(*(const float4*)p, *(const float4*)(p + 4));
    } else {
      af = read_a(hb, kt - 4, grp, row16);
    }
#pragma unroll
    for (int nt = 0; nt < 8; ++nt) {
      bf16x8 bw = *(const bf16x8*)(pnw0 + ((size_t)(kt * 8 + nt) * 64 + lane) * 8);
      acc[nt] = __builtin_amdgcn_mfma_f32_16x16x32_bf16(af, bw, acc[nt], 0, 0, 0);
    }
  }
  asm volatile("s_waitcnt lgkmcnt(0)" ::: "memory");
  __builtin_amdgcn_sched_barrier(0);
  stage_t<true>(hb, acc, grp, row16);
  asm volatile("s_waitcnt lgkmcnt(0)" ::: "memory");
  __builtin_amdgcn_sched_barrier(0);

  f32x4 acc2[8];
#pragma unroll
  for (int nt = 0; nt < 8; ++nt) {
    float b = nb1[nt * 16 + row16];
    acc2[nt] = (f32x4){b, b, b, b};
  }
#pragma unroll
  for (int kt = 0; kt < 4; ++kt) {
    bf16x8 af = read_a(hb, kt, grp, row16);
#pragma unroll
    for (int nt = 0; nt < 8; ++nt) {
      bf16x8 bw = *(const bf16x8*)(pnw1 + ((size_t)(kt * 8 + nt) * 64 + lane) * 8);
      acc2[nt] = __builtin_amdgcn_mfma_f32_16x16x32_bf16(af, bw, acc2[nt], 0, 0, 0);
    }
  }
  asm volatile("s_waitcnt lgkmcnt(0)" ::: "memory");
  __builtin_amdgcn_sched_barrier(0);
  stage_t<true>(hb, acc2, grp, row16);
  asm volatile("s_waitcnt lgkmcnt(0)" ::: "memory");
  __builtin_amdgcn_sched_barrier(0);

  f32x4 acc3[8];
#pragma unroll
  for (int nt = 0; nt < 8; ++nt) {
    float b = nb2[nt * 16 + row16];
    acc3[nt] = (f32x4){b, b, b, b};
  }
#pragma unroll
  for (int kt = 0; kt < 4; ++kt) {
    bf16x8 af = read_a(hb, kt, grp, row16);
#pragma unroll
    for (int nt = 0; nt < 8; ++nt) {
      bf16x8 bw = *(const bf16x8*)(pnw2 + ((size_t)(kt * 8 + nt) * 64 + lane) * 8);
      acc3[nt] = __builtin_amdgcn_mfma_f32_16x16x32_bf16(af, bw, acc3[nt], 0, 0, 0);
    }
  }
  f32x4 accR[8];
#pragma unroll
  for (int nt = 0; nt < 8; ++nt) accR[nt] = (f32x4){0.f, 0.f, 0.f, 0.f};
#pragma unroll
  for (int kt = 0; kt < 4; ++kt) {
    const float* p = nodes + (size_t)rA * DF + kt * 32 + grp * 8;
    bf16x8 af = cvt8(*(const float4*)p, *(const float4*)(p + 4));
#pragma unroll
    for (int nt = 0; nt < 8; ++nt) {
      bf16x8 bw = *(const bf16x8*)(pwn + ((size_t)(kt * 8 + nt) * 64 + lane) * 8);
      accR[nt] = __builtin_amdgcn_mfma_f32_16x16x32_bf16(af, bw, accR[nt], 0, 0, 0);
    }
  }

  float y[8][4];
#pragma unroll
  for (int nt = 0; nt < 8; ++nt)
#pragma unroll
    for (int i = 0; i < 4; ++i) y[nt][i] = acc3[nt][i] + accR[nt][i];

  float mean[4], rstd[4];
#pragma unroll
  for (int i = 0; i < 4; ++i) {
    float s = 0.f;
#pragma unroll
    for (int nt = 0; nt < 8; ++nt) s += y[nt][i];
    s += __shfl_xor(s, 1); s += __shfl_xor(s, 2);
    s += __shfl_xor(s, 4); s += __shfl_xor(s, 8);
    mean[i] = s * (1.0f / 128.0f);
  }
#pragma unroll
  for (int i = 0; i < 4; ++i) {
    float v = 0.f;
#pragma unroll
    for (int nt = 0; nt < 8; ++nt) {
      float d = y[nt][i] - mean[i];
      v += d * d;
    }
    v += __shfl_xor(v, 1); v += __shfl_xor(v, 2);
    v += __shfl_xor(v, 4); v += __shfl_xor(v, 8);
    rstd[i] = rsqrtf(v * (1.0f / 128.0f) + 1e-6f);
  }
#pragma unroll
  for (int nt = 0; nt < 8; ++nt) {
    const float ls = ln_s[nt * 16 + row16];
    const float lb = ln_b[nt * 16 + row16];
#pragma unroll
    for (int i = 0; i < 4; ++i) {
      const int r = rb + grp * 4 + i;
      if (r < N_NODES)
        out[(size_t)r * DF + nt * 16 + row16] = (y[nt][i] - mean[i]) * rstd[i] * ls + lb;
    }
  }
}

// ---------- launch ----------
extern "C" void kernel_launch(void* const* d_in, const int* in_sizes, int n_in,
                              void* d_out, int out_size, void* d_ws, size_t ws_size,
                              hipStream_t stream) {
  const float* nodes     = (const float*)d_in[0];
  const float* edges     = (const float*)d_in[1];
  const int*   senders   = (const int*)d_in[2];
  const int*   receivers = (const int*)d_in[3];
  const float* msg_w0 = (const float*)d_in[4];
  const float* msg_b0 = (const float*)d_in[5];
  const float* msg_w1 = (const float*)d_in[6];
  const float* msg_b1 = (const float*)d_in[7];
  const float* msg_w2 = (const float*)d_in[8];
  const float* msg_b2 = (const float*)d_in[9];
  const float* node_w0 = (const float*)d_in[10];
  const float* node_b0 = (const float*)d_in[11];
  const float* node_w1 = (const float*)d_in[12];
  const float* node_b1 = (const float*)d_in[13];
  const float* node_w2 = (const float*)d_in[14];
  const float* node_b2 = (const float*)d_in[15];
  const float* w_node   = (const float*)d_in[16];
  const float* ln_scale = (const float*)d_in[17];
  const float* ln_bias  = (const float*)d_in[18];

  char* ws = (char*)d_ws;
  float* hsum           = (float*)ws;                          //   5,120,000 B
  unsigned short* pw    = (unsigned short*)(ws + 5120000);     //     327,680 B
  unsigned short* nbf   = (unsigned short*)(ws + 5447680);     //   2,560,000 B
  int* deg              = (int*)(ws + 8007680);                //      40,000 B
  int* cursor           = (int*)(ws + 8047680);                //      40,000 B
  int* rid              = (int*)(ws + 8087680);                //   2,560,000 B
  int* ssend            = (int*)(ws + 10647680);               //   2,560,000 B
  unsigned short* P     = (unsigned short*)(ws + 13207680);    //   2,560,000 B
  unsigned short* Q     = (unsigned short*)(ws + 15767680);    //   2,560,000 B
  unsigned short* rsort = (unsigned short*)(ws + 18327680);    // 163,840,000 B (end ~182 MB)

  zero_deg<<<40, 256, 0, stream>>>(deg);

  pack_prep<<<8140, 256, 0, stream>>>(
      msg_w0, msg_w1, msg_w2, node_w0, node_w1, node_w2, w_node, nodes, receivers,
      pw, nbf, deg);

  scan_kernel<<<1, 1024, 0, stream>>>(deg, cursor);

  scatter_l0<<<N_EDGES / 256 + 157, 256, 0, stream>>>(
      receivers, senders, edges, msg_b0, cursor, ssend, rid, rsort, nbf, pw, P, Q, hsum);

  msg_kernel<<<256, 512, 0, stream>>>(
      rsort, ssend, rid, msg_b1, pw, P, Q, hsum);

  node_kernel<<<313, 128, 0, stream>>>(nodes, hsum, deg, msg_b2,
                                       node_b0, node_b1, node_b2,
                                       pw + 65536,
                                       pw + 81920, pw + 114688, pw + 131072, pw + 147456,
                                       ln_scale, ln_bias, (float*)d_out);
}

// Round 17
// 321.370 us; speedup vs baseline: 1.6870x; 1.6870x over previous
//
#include <hip/hip_runtime.h>

#define DF 128
constexpr int N_NODES = 10000;
constexpr int N_EDGES = 640000;

typedef __bf16 bf16x8 __attribute__((ext_vector_type(8)));
typedef float f32x4 __attribute__((ext_vector_type(4)));

// ---------- helpers ----------
__device__ __forceinline__ unsigned short f2bf(float f) {
  unsigned u = __builtin_bit_cast(unsigned, f);
  u += 0x7fffu + ((u >> 16) & 1u);   // RTNE
  return (unsigned short)(u >> 16);
}

__device__ __forceinline__ bf16x8 cvt8(float4 a, float4 b) {
  bf16x8 r;
  r[0] = (__bf16)a.x; r[1] = (__bf16)a.y; r[2] = (__bf16)a.z; r[3] = (__bf16)a.w;
  r[4] = (__bf16)b.x; r[5] = (__bf16)b.y; r[6] = (__bf16)b.z; r[7] = (__bf16)b.w;
  return r;
}

// stage a 16x128 C-layout tile into a 4KB LDS buffer, XOR-swizzled (HW-verified addresses)
template <bool RELU>
__device__ __forceinline__ void stage_t(char* bufj, const f32x4* accv, int grp, int row16) {
#pragma unroll
  for (int nt = 0; nt < 8; ++nt)
#pragma unroll
    for (int i = 0; i < 4; ++i) {
      const int r = grp * 4 + i;
      const int c = nt * 16 + row16;
      float v = RELU ? fmaxf(accv[nt][i], 0.f) : accv[nt][i];
      *(unsigned short*)(bufj + ((r * 256 + c * 2) ^ ((r & 7) << 4))) = f2bf(v);
    }
}

// read an A-fragment (16 rows x 32 k) from a swizzled 4KB buffer (HW-verified)
__device__ __forceinline__ bf16x8 read_a(const char* bufj, int kt, int grp, int row16) {
  return *(const bf16x8*)(bufj + ((row16 * 256 + kt * 64 + grp * 16) ^ ((row16 & 7) << 4)));
}

// ---------- kernel 0: zero deg (replaces hipMemsetAsync blit) ----------
__global__ void zero_deg(int* __restrict__ deg) {
  int i = blockIdx.x * 256 + threadIdx.x;
  if (i < N_NODES) deg[i] = 0;
}

// ---------- kernel 1: pack weights + nodes->bf16 + receiver histogram (fused) ----------
__global__ void pack_prep(const float* __restrict__ w0, const float* __restrict__ w1,
                          const float* __restrict__ w2, const float* __restrict__ nw0,
                          const float* __restrict__ nw1, const float* __restrict__ nw2,
                          const float* __restrict__ wn, const float* __restrict__ nodes,
                          const int* __restrict__ receivers,
                          unsigned short* __restrict__ dst, unsigned short* __restrict__ nbf,
                          int* __restrict__ deg) {
  int tid = blockIdx.x * blockDim.x + threadIdx.x;
  if (tid < 163840) {
    const float* src; int p;
    if (tid < 49152)       { src = w0;  p = tid; }
    else if (tid < 65536)  { src = w1;  p = tid - 49152; }
    else if (tid < 81920)  { src = w2;  p = tid - 65536; }
    else if (tid < 114688) { src = nw0; p = tid - 81920; }
    else if (tid < 131072) { src = nw1; p = tid - 114688; }
    else if (tid < 147456) { src = nw2; p = tid - 131072; }
    else                   { src = wn;  p = tid - 147456; }
    int i = p & 7, lane = (p >> 3) & 63, tile = p >> 9;
    int nt = tile & 7, kt = tile >> 3;
    int k = kt * 32 + ((lane >> 4) << 3) + i;
    int n = nt * 16 + (lane & 15);
    dst[tid] = f2bf(src[k * 128 + n]);
    return;
  }
  int p = tid - 163840;
  if (p < N_NODES * DF) {                    // nodes -> bf16
    nbf[p] = f2bf(nodes[p]);
    return;
  }
  p -= N_NODES * DF;
  if (p < N_EDGES) atomicAdd(&deg[receivers[p]], 1);
}

// ---------- CSR build: exclusive scan of deg -> cursor ----------
__global__ void scan_kernel(const int* __restrict__ deg, int* __restrict__ cursor) {
  __shared__ int part[1024];
  const int t = threadIdx.x;
  int loc[16];
  int s = 0;
#pragma unroll
  for (int j = 0; j < 16; ++j) {
    int idx = t * 16 + j;
    int v = (idx < N_NODES) ? deg[idx] : 0;
    loc[j] = s;
    s += v;
  }
  part[t] = s;
  __syncthreads();
  for (int off = 1; off < 1024; off <<= 1) {
    int v = part[t];
    int a = (t >= off) ? part[t - off] : 0;
    __syncthreads();
    part[t] = v + a;
    __syncthreads();
  }
  int base = (t > 0) ? part[t - 1] : 0;
#pragma unroll
  for (int j = 0; j < 16; ++j) {
    int idx = t * 16 + j;
    if (idx < N_NODES) cursor[idx] = base + loc[j];
  }
}

// ---------- kernel 3: scatter (blocks 0..2499) + pq & hsum-zero (blocks 2500..2656) ----------
__global__ void __launch_bounds__(256) scatter_pq(
    const int* __restrict__ receivers, const int* __restrict__ senders,
    int* __restrict__ cursor, int2* __restrict__ ep, int* __restrict__ rid,
    const unsigned short* __restrict__ nbf, const unsigned short* __restrict__ pw,
    unsigned short* __restrict__ P, unsigned short* __restrict__ Q,
    float* __restrict__ hsum) {
  const int bid = blockIdx.x;
  const int tid = threadIdx.x;
  if (bid < N_EDGES / 256) {
    int e = bid * 256 + tid;
    int r = receivers[e];
    int q = atomicAdd(&cursor[r], 1);
    ep[q] = make_int2(e, senders[e]);
    rid[q] = r;
    return;
  }
  const int pb = bid - N_EDGES / 256;   // 0..156
  const int base_row = pb * 64;
  const int nrows = min(64, N_NODES - base_row);
  {
    float4* hz = (float4*)(hsum + (size_t)base_row * DF);
    for (int c = tid; c < nrows * 32; c += 256) hz[c] = make_float4(0.f, 0.f, 0.f, 0.f);
  }
  const int lane = tid & 63, wave = tid >> 6;
  const int row16 = lane & 15, grp = lane >> 4;
  const int rb = base_row + wave * 16;
  const int rA = min(rb + row16, N_NODES - 1);

  f32x4 aP[8], aQ[8];
#pragma unroll
  for (int nt = 0; nt < 8; ++nt) {
    aP[nt] = (f32x4){0.f, 0.f, 0.f, 0.f};
    aQ[nt] = (f32x4){0.f, 0.f, 0.f, 0.f};
  }
#pragma unroll
  for (int kt = 0; kt < 4; ++kt) {
    bf16x8 af = *(const bf16x8*)(nbf + (size_t)rA * DF + kt * 32 + grp * 8);
#pragma unroll
    for (int nt = 0; nt < 8; ++nt) {
      bf16x8 bwP = *(const bf16x8*)(pw + ((size_t)(kt * 8 + nt) * 64 + lane) * 8);
      bf16x8 bwQ = *(const bf16x8*)(pw + ((size_t)((4 + kt) * 8 + nt) * 64 + lane) * 8);
      aP[nt] = __builtin_amdgcn_mfma_f32_16x16x32_bf16(af, bwP, aP[nt], 0, 0, 0);
      aQ[nt] = __builtin_amdgcn_mfma_f32_16x16x32_bf16(af, bwQ, aQ[nt], 0, 0, 0);
    }
  }
#pragma unroll
  for (int nt = 0; nt < 8; ++nt)
#pragma unroll
    for (int i = 0; i < 4; ++i) {
      const int r = rb + grp * 4 + i;
      if (r < N_NODES) {
        P[(size_t)r * DF + nt * 16 + row16] = f2bf(aP[nt][i]);
        Q[(size_t)r * DF + nt * 16 + row16] = f2bf(aQ[nt][i]);
      }
    }
}

// ---------- kernel 4: persistent edge MLP through h2 + scatter-add of h2 ----------
// grid 256 x 512 thr; each block loops over tiles (tile = bid, bid+256, ...),
// 256 sorted positions/tile, 8 waves x 32. Weights in LDS once per block.
// (r12/r14-proven config: 8 waves/CU keeps hsum atomics L2-resident.)
__global__ void __launch_bounds__(512, 2) msg_kernel(
    const float* __restrict__ edges,
    const int2* __restrict__ ep, const int* __restrict__ rid,
    const float* __restrict__ b0, const float* __restrict__ b1,
    const unsigned short* __restrict__ pw,
    const unsigned short* __restrict__ P, const unsigned short* __restrict__ Q,
    float* __restrict__ hsum) {
  __shared__ char lds[131072];
  // [0,32768): W0c frags; [32768,65536): W1 frags; [65536+wave*8192): h-tiles
  const int tid = threadIdx.x;
  const int lane = tid & 63, wave = tid >> 6;
  const int row16 = lane & 15, grp = lane >> 4;
  char* hb = lds + 65536 + wave * 8192;

  // ---- stage W0c + W1 (64KB) once per block ----
  {
    const float4* src = (const float4*)(pw + 32768);
    float4* dst = (float4*)lds;
    for (int c = tid; c < 4096; c += 512) dst[c] = src[c];
  }

  constexpr int NTILE = N_EDGES / 256;   // 2500
  int tile = blockIdx.x;

  // loop-carried state
  float4 t0[4][2], t1[4][2];
  int sxc[2], rxc[2];
  int e2_[2], sx2[2], rx2[2];

  // ---- prologue: indices + edge loads for first tile ----
  {
    const int pb = tile * 256 + wave * 32;
#pragma unroll
    for (int s = 0; s < 2; ++s) {
      int2 es = ep[pb + s * 16 + row16];
      e2_[s] = es.x; sx2[s] = es.y;
      rx2[s] = rid[pb + s * 16 + row16];
    }
#pragma unroll
    for (int k2 = 0; k2 < 4; ++k2) {
      const float* p0 = edges + (size_t)e2_[0] * DF + k2 * 32 + grp * 8;
      const float* p1 = edges + (size_t)e2_[1] * DF + k2 * 32 + grp * 8;
      t0[k2][0] = *(const float4*)p0; t0[k2][1] = *(const float4*)(p0 + 4);
      t1[k2][0] = *(const float4*)p1; t1[k2][1] = *(const float4*)(p1 + 4);
    }
    sxc[0] = sx2[0]; sxc[1] = sx2[1];
    rxc[0] = rx2[0]; rxc[1] = rx2[1];
  }

  __syncthreads();   // weights staged

  for (; tile < NTILE; tile += 256) {
    const int pbase = tile * 256 + wave * 32;
    const bool hasNext = (tile + 256) < NTILE;

    // A. issue next-tile index loads (independent of everything below)
    if (hasNext) {
      const int npb = (tile + 256) * 256 + wave * 32;
#pragma unroll
      for (int s = 0; s < 2; ++s) {
        int2 es = ep[npb + s * 16 + row16];
        e2_[s] = es.x; sx2[s] = es.y;
        rx2[s] = rid[npb + s * 16 + row16];
      }
    }

    // B. convert current-tile edges (waits on last iteration's loads)
    bf16x8 ebf[2][4];
#pragma unroll
    for (int k2 = 0; k2 < 4; ++k2) {
      ebf[0][k2] = cvt8(t0[k2][0], t0[k2][1]);
      ebf[1][k2] = cvt8(t1[k2][0], t1[k2][1]);
    }

    // C. P/Q prefetch for current tile (consumed in L1; hidden under L0)
    bf16x8 pqf[2][2][4];   // [s][0=P,1=Q][kt]
#pragma unroll
    for (int s = 0; s < 2; ++s)
#pragma unroll
      for (int kt = 0; kt < 4; ++kt) {
        pqf[s][0][kt] = *(const bf16x8*)(P + (size_t)sxc[s] * DF + kt * 32 + grp * 8);
        pqf[s][1][kt] = *(const bf16x8*)(Q + (size_t)rxc[s] * DF + kt * 32 + grp * 8);
      }

    // D. layer 0 (edge part): K=128, weights from LDS
    f32x4 acc[2][8];
#pragma unroll
    for (int nt = 0; nt < 8; ++nt) {
      float bv = b0[nt * 16 + row16];
      acc[0][nt] = (f32x4){bv, bv, bv, bv};
      acc[1][nt] = (f32x4){bv, bv, bv, bv};
    }
#pragma unroll
    for (int kt = 0; kt < 4; ++kt) {
#pragma unroll
      for (int nt = 0; nt < 8; ++nt) {
        bf16x8 bw = *(const bf16x8*)(lds + ((kt * 8 + nt) * 64 + lane) * 16);
        acc[0][nt] = __builtin_amdgcn_mfma_f32_16x16x32_bf16(ebf[0][kt], bw, acc[0][nt], 0, 0, 0);
        acc[1][nt] = __builtin_amdgcn_mfma_f32_16x16x32_bf16(ebf[1][kt], bw, acc[1][nt], 0, 0, 0);
      }
    }

    // E. issue next-tile edge loads (HBM; consumed at next iteration's B)
    if (hasNext) {
#pragma unroll
      for (int k2 = 0; k2 < 4; ++k2) {
        const float* p0 = edges + (size_t)e2_[0] * DF + k2 * 32 + grp * 8;
        const float* p1 = edges + (size_t)e2_[1] * DF + k2 * 32 + grp * 8;
        t0[k2][0] = *(const float4*)p0; t0[k2][1] = *(const float4*)(p0 + 4);
        t1[k2][0] = *(const float4*)p1; t1[k2][1] = *(const float4*)(p1 + 4);
      }
    }

    // F. transpose raw (E@W0c + b0) into per-wave h-tiles
    stage_t<false>(hb, acc[0], grp, row16);
    stage_t<false>(hb + 4096, acc[1], grp, row16);
    asm volatile("s_waitcnt lgkmcnt(0)" ::: "memory");
    __builtin_amdgcn_sched_barrier(0);

    // G. layer 1 with fused h1 = relu(staged + P[s] + Q[r]); acc reused
#pragma unroll
    for (int nt = 0; nt < 8; ++nt) {
      float bv = b1[nt * 16 + row16];
      acc[0][nt] = (f32x4){bv, bv, bv, bv};
      acc[1][nt] = (f32x4){bv, bv, bv, bv};
    }
#pragma unroll
    for (int kt = 0; kt < 4; ++kt) {
      bf16x8 af[2];
#pragma unroll
      for (int s = 0; s < 2; ++s) {
        bf16x8 raw = read_a(hb + s * 4096, kt, grp, row16);
        bf16x8 pv = pqf[s][0][kt], qv = pqf[s][1][kt];
        bf16x8 h;
#pragma unroll
        for (int j = 0; j < 8; ++j)
          h[j] = (__bf16)fmaxf((float)raw[j] + (float)pv[j] + (float)qv[j], 0.f);
        af[s] = h;
      }
#pragma unroll
      for (int nt = 0; nt < 8; ++nt) {
        bf16x8 bw = *(const bf16x8*)(lds + 32768 + ((kt * 8 + nt) * 64 + lane) * 16);
        acc[0][nt] = __builtin_amdgcn_mfma_f32_16x16x32_bf16(af[0], bw, acc[0][nt], 0, 0, 0);
        acc[1][nt] = __builtin_amdgcn_mfma_f32_16x16x32_bf16(af[1], bw, acc[1][nt], 0, 0, 0);
      }
    }

    // H. epilogue: scatter-add h2 = relu(acc) via register segmented reduction
#pragma unroll
    for (int s = 0; s < 2; ++s) {
      const int q = pbase + s * 16 + grp * 4;
      const int ru = rid[pbase + s * 16];                 // wave-uniform
      const bool uni = (ru == rid[pbase + s * 16 + 15]);  // whole subtile one receiver
      if (uni) {
#pragma unroll
        for (int nt = 0; nt < 8; ++nt) {
          float t = fmaxf(acc[s][nt][0], 0.f) + fmaxf(acc[s][nt][1], 0.f) +
                    fmaxf(acc[s][nt][2], 0.f) + fmaxf(acc[s][nt][3], 0.f);
          t += __shfl_xor(t, 16);
          t += __shfl_xor(t, 32);
          if (grp == 0)
            unsafeAtomicAdd(hsum + (size_t)ru * DF + nt * 16 + row16, t);
        }
      } else {
        const int ra = rid[q], rb_ = rid[q + 1], rc = rid[q + 2], rd = rid[q + 3];
#pragma unroll
        for (int nt = 0; nt < 8; ++nt) {
          const int col = nt * 16 + row16;
          float run = fmaxf(acc[s][nt][0], 0.f);
          if (rb_ != ra) { unsafeAtomicAdd(hsum + (size_t)ra * DF + col, run); run = 0.f; }
          run += fmaxf(acc[s][nt][1], 0.f);
          if (rc != rb_) { unsafeAtomicAdd(hsum + (size_t)rb_ * DF + col, run); run = 0.f; }
          run += fmaxf(acc[s][nt][2], 0.f);
          if (rd != rc) { unsafeAtomicAdd(hsum + (size_t)rc * DF + col, run); run = 0.f; }
          run += fmaxf(acc[s][nt][3], 0.f);
          unsafeAtomicAdd(hsum + (size_t)rd * DF + col, run);
        }
      }
    }

    // I. rotate indices; fence h-tile WAR before next iteration's stage_t
    sxc[0] = sx2[0]; sxc[1] = sx2[1];
    rxc[0] = rx2[0]; rxc[1] = rx2[1];
    asm volatile("s_waitcnt lgkmcnt(0)" ::: "memory");
    __builtin_amdgcn_sched_barrier(0);
  }
}

// ---------- kernel 5: agg = hsum@W2 + deg*b2 (hi/lo bf16), node MLP, residual, LN ----------
// 128 thr = 2 waves x 16 rows, grid 313
__global__ void __launch_bounds__(128) node_kernel(
    const float* __restrict__ nodes, const float* __restrict__ hsum,
    const int* __restrict__ deg, const float* __restrict__ b2,
    const float* __restrict__ nb0, const float* __restrict__ nb1, const float* __restrict__ nb2,
    const unsigned short* __restrict__ pw2,
    const unsigned short* __restrict__ pnw0, const unsigned short* __restrict__ pnw1,
    const unsigned short* __restrict__ pnw2, const unsigned short* __restrict__ pwn,
    const float* __restrict__ ln_s, const float* __restrict__ ln_b,
    float* __restrict__ out) {
  __shared__ char hs[8192];
  const int tid = threadIdx.x, lane = tid & 63, wave = tid >> 6;
  const int row16 = lane & 15, grp = lane >> 4;
  char* hb = hs + wave * 4096;
  const int rb = blockIdx.x * 32 + wave * 16;
  const int rA = min(rb + row16, N_NODES - 1);

  // ---- phase A: aggregated = hsum @ W2 + deg*b2 (hi/lo split for precision) ----
  f32x4 accA[8];
  {
    float d0 = (float)deg[min(rb + grp * 4 + 0, N_NODES - 1)];
    float d1 = (float)deg[min(rb + grp * 4 + 1, N_NODES - 1)];
    float d2 = (float)deg[min(rb + grp * 4 + 2, N_NODES - 1)];
    float d3 = (float)deg[min(rb + grp * 4 + 3, N_NODES - 1)];
#pragma unroll
    for (int nt = 0; nt < 8; ++nt) {
      float bc = b2[nt * 16 + row16];
      accA[nt] = (f32x4){d0 * bc, d1 * bc, d2 * bc, d3 * bc};
    }
  }
#pragma unroll
  for (int kt = 0; kt < 4; ++kt) {
    const float* hp = hsum + (size_t)rA * DF + kt * 32 + grp * 8;
    float4 h0 = *(const float4*)hp, h1v = *(const float4*)(hp + 4);
    bf16x8 hi = cvt8(h0, h1v);
    float4 l0, l1;
    l0.x = h0.x - (float)hi[0]; l0.y = h0.y - (float)hi[1];
    l0.z = h0.z - (float)hi[2]; l0.w = h0.w - (float)hi[3];
    l1.x = h1v.x - (float)hi[4]; l1.y = h1v.y - (float)hi[5];
    l1.z = h1v.z - (float)hi[6]; l1.w = h1v.w - (float)hi[7];
    bf16x8 lo = cvt8(l0, l1);
#pragma unroll
    for (int nt = 0; nt < 8; ++nt) {
      bf16x8 bw = *(const bf16x8*)(pw2 + ((size_t)(kt * 8 + nt) * 64 + lane) * 8);
      accA[nt] = __builtin_amdgcn_mfma_f32_16x16x32_bf16(hi, bw, accA[nt], 0, 0, 0);
      accA[nt] = __builtin_amdgcn_mfma_f32_16x16x32_bf16(lo, bw, accA[nt], 0, 0, 0);
    }
  }
  stage_t<false>(hb, accA, grp, row16);   // raw (aggregated can be negative)
  asm volatile("s_waitcnt lgkmcnt(0)" ::: "memory");
  __builtin_amdgcn_sched_barrier(0);

  // ---- node layer 0: K=256 = [nodes | aggregated] ----
  f32x4 acc[8];
#pragma unroll
  for (int nt = 0; nt < 8; ++nt) {
    float b = nb0[nt * 16 + row16];
    acc[nt] = (f32x4){b, b, b, b};
  }
#pragma unroll
  for (int kt = 0; kt < 8; ++kt) {
    bf16x8 af;
    if (kt < 4) {
      const float* p = nodes + (size_t)rA * DF + kt * 32 + grp * 8;
      af = cvt8(*(const float4*)p, *(const float4*)(p + 4));
    } else {
      af = read_a(hb, kt - 4, grp, row16);
    }
#pragma unroll
    for (int nt = 0; nt < 8; ++nt) {
      bf16x8 bw = *(const bf16x8*)(pnw0 + ((size_t)(kt * 8 + nt) * 64 + lane) * 8);
      acc[nt] = __builtin_amdgcn_mfma_f32_16x16x32_bf16(af, bw, acc[nt], 0, 0, 0);
    }
  }
  asm volatile("s_waitcnt lgkmcnt(0)" ::: "memory");
  __builtin_amdgcn_sched_barrier(0);
  stage_t<true>(hb, acc, grp, row16);
  asm volatile("s_waitcnt lgkmcnt(0)" ::: "memory");
  __builtin_amdgcn_sched_barrier(0);

  f32x4 acc2[8];
#pragma unroll
  for (int nt = 0; nt < 8; ++nt) {
    float b = nb1[nt * 16 + row16];
    acc2[nt] = (f32x4){b, b, b, b};
  }
#pragma unroll
  for (int kt = 0; kt < 4; ++kt) {
    bf16x8 af = read_a(hb, kt, grp, row16);
#pragma unroll
    for (int nt = 0; nt < 8; ++nt) {
      bf16x8 bw = *(const bf16x8*)(pnw1 + ((size_t)(kt * 8 + nt) * 64 + lane) * 8);
      acc2[nt] = __builtin_amdgcn_mfma_f32_16x16x32_bf16(af, bw, acc2[nt], 0, 0, 0);
    }
  }
  asm volatile("s_waitcnt lgkmcnt(0)" ::: "memory");
  __builtin_amdgcn_sched_barrier(0);
  stage_t<true>(hb, acc2, grp, row16);
  asm volatile("s_waitcnt lgkmcnt(0)" ::: "memory");
  __builtin_amdgcn_sched_barrier(0);

  f32x4 acc3[8];
#pragma unroll
  for (int nt = 0; nt < 8; ++nt) {
    float b = nb2[nt * 16 + row16];
    acc3[nt] = (f32x4){b, b, b, b};
  }
#pragma unroll
  for (int kt = 0; kt < 4; ++kt) {
    bf16x8 af = read_a(hb, kt, grp, row16);
#pragma unroll
    for (int nt = 0; nt < 8; ++nt) {
      bf16x8 bw = *(const bf16x8*)(pnw2 + ((size_t)(kt * 8 + nt) * 64 + lane) * 8);
      acc3[nt] = __builtin_amdgcn_mfma_f32_16x16x32_bf16(af, bw, acc3[nt], 0, 0, 0);
    }
  }
  f32x4 accR[8];
#pragma unroll
  for (int nt = 0; nt < 8; ++nt) accR[nt] = (f32x4){0.f, 0.f, 0.f, 0.f};
#pragma unroll
  for (int kt = 0; kt < 4; ++kt) {
    const float* p = nodes + (size_t)rA * DF + kt * 32 + grp * 8;
    bf16x8 af = cvt8(*(const float4*)p, *(const float4*)(p + 4));
#pragma unroll
    for (int nt = 0; nt < 8; ++nt) {
      bf16x8 bw = *(const bf16x8*)(pwn + ((size_t)(kt * 8 + nt) * 64 + lane) * 8);
      accR[nt] = __builtin_amdgcn_mfma_f32_16x16x32_bf16(af, bw, accR[nt], 0, 0, 0);
    }
  }

  float y[8][4];
#pragma unroll
  for (int nt = 0; nt < 8; ++nt)
#pragma unroll
    for (int i = 0; i < 4; ++i) y[nt][i] = acc3[nt][i] + accR[nt][i];

  float mean[4], rstd[4];
#pragma unroll
  for (int i = 0; i < 4; ++i) {
    float s = 0.f;
#pragma unroll
    for (int nt = 0; nt < 8; ++nt) s += y[nt][i];
    s += __shfl_xor(s, 1); s += __shfl_xor(s, 2);
    s += __shfl_xor(s, 4); s += __shfl_xor(s, 8);
    mean[i] = s * (1.0f / 128.0f);
  }
#pragma unroll
  for (int i = 0; i < 4; ++i) {
    float v = 0.f;
#pragma unroll
    for (int nt = 0; nt < 8; ++nt) {
      float d = y[nt][i] - mean[i];
      v += d * d;
    }
    v += __shfl_xor(v, 1); v += __shfl_xor(v, 2);
    v += __shfl_xor(v, 4); v += __shfl_xor(v, 8);
    rstd[i] = rsqrtf(v * (1.0f / 128.0f) + 1e-6f);
  }
#pragma unroll
  for (int nt = 0; nt < 8; ++nt) {
    const float ls = ln_s[nt * 16 + row16];
    const float lb = ln_b[nt * 16 + row16];
#pragma unroll
    for (int i = 0; i < 4; ++i) {
      const int r = rb + grp * 4 + i;
      if (r < N_NODES)
        out[(size_t)r * DF + nt * 16 + row16] = (y[nt][i] - mean[i]) * rstd[i] * ls + lb;
    }
  }
}

// ---------- launch ----------
extern "C" void kernel_launch(void* const* d_in, const int* in_sizes, int n_in,
                              void* d_out, int out_size, void* d_ws, size_t ws_size,
                              hipStream_t stream) {
  const float* nodes     = (const float*)d_in[0];
  const float* edges     = (const float*)d_in[1];
  const int*   senders   = (const int*)d_in[2];
  const int*   receivers = (const int*)d_in[3];
  const float* msg_w0 = (const float*)d_in[4];
  const float* msg_b0 = (const float*)d_in[5];
  const float* msg_w1 = (const float*)d_in[6];
  const float* msg_b1 = (const float*)d_in[7];
  const float* msg_w2 = (const float*)d_in[8];
  const float* msg_b2 = (const float*)d_in[9];
  const float* node_w0 = (const float*)d_in[10];
  const float* node_b0 = (const float*)d_in[11];
  const float* node_w1 = (const float*)d_in[12];
  const float* node_b1 = (const float*)d_in[13];
  const float* node_w2 = (const float*)d_in[14];
  const float* node_b2 = (const float*)d_in[15];
  const float* w_node   = (const float*)d_in[16];
  const float* ln_scale = (const float*)d_in[17];
  const float* ln_bias  = (const float*)d_in[18];

  char* ws = (char*)d_ws;
  float* hsum           = (float*)ws;                          // 5,120,000 B
  unsigned short* pw    = (unsigned short*)(ws + 5120000);     //   327,680 B
  unsigned short* nbf   = (unsigned short*)(ws + 5447680);     // 2,560,000 B
  int* deg              = (int*)(ws + 8007680);                //    40,000 B
  int* cursor           = (int*)(ws + 8047680);                //    40,000 B
  int* rid              = (int*)(ws + 8087680);                // 2,560,000 B
  int2* ep              = (int2*)(ws + 10647680);              // 5,120,000 B (8B aligned)
  unsigned short* P     = (unsigned short*)(ws + 15767680);    // 2,560,000 B (16B aligned)
  unsigned short* Q     = (unsigned short*)(ws + 18327680);    // 2,560,000 B (end ~20.9 MB)

  zero_deg<<<40, 256, 0, stream>>>(deg);

  pack_prep<<<8140, 256, 0, stream>>>(
      msg_w0, msg_w1, msg_w2, node_w0, node_w1, node_w2, w_node, nodes, receivers,
      pw, nbf, deg);

  scan_kernel<<<1, 1024, 0, stream>>>(deg, cursor);

  scatter_pq<<<N_EDGES / 256 + 157, 256, 0, stream>>>(
      receivers, senders, cursor, ep, rid, nbf, pw, P, Q, hsum);

  msg_kernel<<<256, 512, 0, stream>>>(
      edges, ep, rid, msg_b0, msg_b1, pw, P, Q, hsum);

  node_kernel<<<313, 128, 0, stream>>>(nodes, hsum, deg, msg_b2,
                                       node_b0, node_b1, node_b2,
                                       pw + 65536,
                                       pw + 81920, pw + 114688, pw + 131072, pw + 147456,
                                       ln_scale, ln_bias, (float*)d_out);
}